// Round 7
// baseline (335.683 us; speedup 1.0000x reference)
//
#include <hip/hip_runtime.h>

#define N_NODES 50000
#define N_EDGES 800000
#define D_FEAT 128
#define LN_EPS 1e-5f
#define TM 32          // nodes per block in fused kernel
#define KB 32          // K-chunk
#define AS_STRIDE 260  // A-tile row stride in floats (256 + 4 pad, 16B-aligned)
#define NBLK 196       // ceil(N_NODES/256) scan blocks

// ---------------------------------------------------------------------------
// zero the degree counters (ws is poisoned 0xAA every call)
// ---------------------------------------------------------------------------
__global__ void zero_kernel(int* __restrict__ p, int n)
{
    int i = blockIdx.x * 256 + threadIdx.x;
    if (i < n) p[i] = 0;
}

// ---------------------------------------------------------------------------
// histogram of destination nodes
// ---------------------------------------------------------------------------
__global__ void hist_kernel(const int* __restrict__ ei, int* __restrict__ deg_cnt)
{
    int e = blockIdx.x * 256 + threadIdx.x;
    if (e >= N_EDGES) return;
    int dst = ei[N_EDGES + e];
    dst = (dst < 0) ? 0 : ((dst >= N_NODES) ? (N_NODES - 1) : dst);
    atomicAdd(&deg_cnt[dst], 1);
}

// ---------------------------------------------------------------------------
// scan phase 1: per-block (256-elem chunk) sum of deg_cnt -> bsum[block]
// ---------------------------------------------------------------------------
__global__ void blocksum_kernel(const int* __restrict__ deg_cnt, int* __restrict__ bsum)
{
    __shared__ int ws[4];
    int b = blockIdx.x, t = threadIdx.x;
    int i = b * 256 + t;
    int v = (i < N_NODES) ? deg_cnt[i] : 0;
    #pragma unroll
    for (int off = 1; off < 64; off <<= 1) v += __shfl_xor(v, off, 64);
    if ((t & 63) == 0) ws[t >> 6] = v;
    __syncthreads();
    if (t == 0) bsum[b] = ws[0] + ws[1] + ws[2] + ws[3];
}

// ---------------------------------------------------------------------------
// scan phase 2: exclusive scan of the 196 block sums (single small block)
// ---------------------------------------------------------------------------
__global__ void scanblk_kernel(const int* __restrict__ bsum, int* __restrict__ boff)
{
    __shared__ int s[256];
    int t = threadIdx.x;
    int v = (t < NBLK) ? bsum[t] : 0;
    s[t] = v;
    __syncthreads();
    for (int off = 1; off < 256; off <<= 1) {
        int u = (t >= off) ? s[t - off] : 0;
        __syncthreads();
        s[t] += u;
        __syncthreads();
    }
    if (t < NBLK) boff[t] = s[t] - v;   // exclusive
}

// ---------------------------------------------------------------------------
// scan phase 3: block-local exclusive scan + block offset -> pos
// ---------------------------------------------------------------------------
__global__ void scanpos_kernel(const int* __restrict__ deg_cnt,
                               const int* __restrict__ boff,
                               int* __restrict__ pos)
{
    __shared__ int s[256];
    int b = blockIdx.x, t = threadIdx.x;
    int i = b * 256 + t;
    int v = (i < N_NODES) ? deg_cnt[i] : 0;
    s[t] = v;
    __syncthreads();
    for (int off = 1; off < 256; off <<= 1) {
        int u = (t >= off) ? s[t - off] : 0;
        __syncthreads();
        s[t] += u;
        __syncthreads();
    }
    if (i < N_NODES) pos[i] = boff[b] + s[t] - v;   // exclusive global
}

// ---------------------------------------------------------------------------
// bucket fill: edge_src[slot] = src, slot = pos[dst]++  (after this, pos = end)
// ---------------------------------------------------------------------------
__global__ void fill_kernel(const int* __restrict__ ei, int* __restrict__ pos,
                            int* __restrict__ edge_src)
{
    int e = blockIdx.x * 256 + threadIdx.x;
    if (e >= N_EDGES) return;
    int src = ei[e];
    int dst = ei[N_EDGES + e];
    src = (src < 0) ? 0 : ((src >= N_NODES) ? (N_NODES - 1) : src);
    dst = (dst < 0) ? 0 : ((dst >= N_NODES) ? (N_NODES - 1) : dst);
    int slot = atomicAdd(&pos[dst], 1);
    edge_src[slot] = src;
}

// ---------------------------------------------------------------------------
// weight prep.  Wt2 layout [k][n], k<128 -> W1 (verbatim copy of W's first
// half); k>=128 -> M = agg_W @ W2.  cvec[n] = b[n] + sum_j agg_b[j]*W2[j][n].
// ---------------------------------------------------------------------------
__global__ void wprep_kernel(const float* __restrict__ agg_W,
                             const float* __restrict__ agg_b,
                             const float* __restrict__ W,
                             const float* __restrict__ b,
                             float* __restrict__ Wt2,
                             float* __restrict__ cvec)
{
    int t = blockIdx.x;    // 0..127
    int n = threadIdx.x;   // 0..127

    Wt2[t * 128 + n] = W[t * 128 + n];            // W1 half, already [k][n]

    float m = 0.0f;
    for (int j = 0; j < 128; ++j)
        m += agg_W[t * 128 + j] * W[(128 + j) * 128 + n];
    Wt2[(128 + t) * 128 + n] = m;

    if (t == 0) {
        float s = b[n];
        for (int j = 0; j < 128; ++j)
            s += agg_b[j] * W[(128 + j) * 128 + n];
        cvec[n] = s;
    }
}

// ---------------------------------------------------------------------------
// FUSED: per-block gather (CSR mean -> LDS) + GEMM + ReLU + LayerNorm.
// 256 threads (4 waves), TM=32 nodes per block.
//   phase 1: stage x half of A (coalesced float4), gather agg half
//            (wave per node, 2 edges/iter via half-waves, float4 row reads)
//   phase 2: K-chunked GEMM vs LDS-staged W chunks, 4x4 accs per thread
//   phase 3: +c, ReLU, LN (shfl reduce over 32 col-lanes), float4 store
// ---------------------------------------------------------------------------
__global__ __launch_bounds__(256) void gsage_fused(
        const float* __restrict__ x,
        const int* __restrict__ pos,       // = segment end after fill
        const int* __restrict__ deg_cnt,
        const int* __restrict__ edge_src,
        const float* __restrict__ Wt2,
        const float* __restrict__ cvec,
        const float* __restrict__ gamma,
        const float* __restrict__ beta,
        float* __restrict__ out)
{
    __shared__ float AS[TM * AS_STRIDE];   // 33.3 KB: [x(0..127) | agg(128..255)]
    __shared__ float Wc[KB * 128];         // 16 KB

    int tid   = threadIdx.x;
    int node0 = blockIdx.x * TM;
    int wv    = tid >> 6;
    int lane  = tid & 63;
    int half  = lane >> 5;
    int sub   = lane & 31;

    // ---- phase 1a: stage x half of A (coalesced) ----
    #pragma unroll
    for (int it = 0; it < 4; ++it) {
        int idx = it * 256 + tid;
        int r   = idx >> 5;             // local node
        int kk4 = (idx & 31) * 4;       // feature offset
        int node = node0 + r;
        float4 v = make_float4(0.f, 0.f, 0.f, 0.f);
        if (node < N_NODES)
            v = *(const float4*)(x + (size_t)node * D_FEAT + kk4);
        *(float4*)&AS[r * AS_STRIDE + kk4] = v;
    }

    // ---- phase 1b: gather agg half; wave wv owns local nodes wv*8..wv*8+7 ----
    for (int i = 0; i < 8; ++i) {
        int nl   = wv * 8 + i;
        int node = node0 + nl;
        float4 acc = make_float4(0.f, 0.f, 0.f, 0.f);
        int dcnt = 0;
        if (node < N_NODES) {
            int end   = pos[node];
            dcnt      = deg_cnt[node];
            int start = end - dcnt;
            for (int b = start; b < end; b += 64) {
                int nb = end - b; if (nb > 64) nb = 64;
                int sid = (b + lane < end) ? edge_src[b + lane] : 0;
                for (int j = 0; j < nb; j += 2) {
                    int eidx = j + half;                 // half-wave per edge
                    int s = __shfl(sid, eidx, 64);
                    if (eidx < nb) {
                        const float4 v = *(const float4*)(x + (size_t)s * D_FEAT + sub * 4);
                        acc.x += v.x; acc.y += v.y; acc.z += v.z; acc.w += v.w;
                    }
                }
            }
        }
        // cross-half reduce (lane ^ 32)
        acc.x += __shfl_xor(acc.x, 32, 64);
        acc.y += __shfl_xor(acc.y, 32, 64);
        acc.z += __shfl_xor(acc.z, 32, 64);
        acc.w += __shfl_xor(acc.w, 32, 64);
        if (half == 0) {
            float inv = 1.0f / (float)((dcnt > 1) ? dcnt : 1);
            float4 m;
            m.x = acc.x * inv; m.y = acc.y * inv;
            m.z = acc.z * inv; m.w = acc.w * inv;
            *(float4*)&AS[nl * AS_STRIDE + 128 + sub * 4] = m;   // zeros if OOB node
        }
    }
    __syncthreads();

    // ---- phase 2: GEMM, K=256 in chunks of 32 ----
    int tx = tid & 31;
    int ty = tid >> 5;

    float acc[4][4];
    #pragma unroll
    for (int i = 0; i < 4; ++i)
        #pragma unroll
        for (int j = 0; j < 4; ++j) acc[i][j] = 0.0f;

    for (int c = 0; c < 256 / KB; ++c) {
        int k0 = c * KB;
        // stage W chunk (16 KB contiguous, coalesced)
        {
            const float4* src = (const float4*)(Wt2 + k0 * 128);
            float4* dstp = (float4*)Wc;
            #pragma unroll
            for (int i = 0; i < 4; ++i)
                dstp[i * 256 + tid] = src[i * 256 + tid];
        }
        __syncthreads();

        #pragma unroll 8
        for (int kk = 0; kk < KB; ++kk) {
            float a0 = AS[(ty * 4 + 0) * AS_STRIDE + k0 + kk];
            float a1 = AS[(ty * 4 + 1) * AS_STRIDE + k0 + kk];
            float a2 = AS[(ty * 4 + 2) * AS_STRIDE + k0 + kk];
            float a3 = AS[(ty * 4 + 3) * AS_STRIDE + k0 + kk];
            float4 w = *(const float4*)&Wc[kk * 128 + tx * 4];
            acc[0][0] += a0 * w.x; acc[0][1] += a0 * w.y; acc[0][2] += a0 * w.z; acc[0][3] += a0 * w.w;
            acc[1][0] += a1 * w.x; acc[1][1] += a1 * w.y; acc[1][2] += a1 * w.z; acc[1][3] += a1 * w.w;
            acc[2][0] += a2 * w.x; acc[2][1] += a2 * w.y; acc[2][2] += a2 * w.z; acc[2][3] += a2 * w.w;
            acc[3][0] += a3 * w.x; acc[3][1] += a3 * w.y; acc[3][2] += a3 * w.z; acc[3][3] += a3 * w.w;
        }
        __syncthreads();
    }

    // ---- phase 3: +c, ReLU, LayerNorm over 128 cols (32 tx lanes) ----
    float4 cv = *(const float4*)(cvec  + tx * 4);
    float4 gv = *(const float4*)(gamma + tx * 4);
    float4 bv = *(const float4*)(beta  + tx * 4);

    #pragma unroll
    for (int i = 0; i < 4; ++i) {
        float v0 = acc[i][0] + cv.x; v0 = (v0 > 0.f) ? v0 : 0.f;
        float v1 = acc[i][1] + cv.y; v1 = (v1 > 0.f) ? v1 : 0.f;
        float v2 = acc[i][2] + cv.z; v2 = (v2 > 0.f) ? v2 : 0.f;
        float v3 = acc[i][3] + cv.w; v3 = (v3 > 0.f) ? v3 : 0.f;
        float s1 = v0 + v1 + v2 + v3;
        float s2 = v0*v0 + v1*v1 + v2*v2 + v3*v3;
        #pragma unroll
        for (int m = 1; m < 32; m <<= 1) {
            s1 += __shfl_xor(s1, m, 64);
            s2 += __shfl_xor(s2, m, 64);
        }
        float mu   = s1 * (1.0f / 128.0f);
        float var  = s2 * (1.0f / 128.0f) - mu * mu;
        float rstd = rsqrtf(var + LN_EPS);
        int node = node0 + ty * 4 + i;
        if (node < N_NODES) {
            float4 o;
            o.x = (v0 - mu) * rstd * gv.x + bv.x;
            o.y = (v1 - mu) * rstd * gv.y + bv.y;
            o.z = (v2 - mu) * rstd * gv.z + bv.z;
            o.w = (v3 - mu) * rstd * gv.w + bv.w;
            *(float4*)(out + (size_t)node * D_FEAT + tx * 4) = o;
        }
    }
}

// ---------------------------------------------------------------------------
extern "C" void kernel_launch(void* const* d_in, const int* in_sizes, int n_in,
                              void* d_out, int out_size, void* d_ws, size_t ws_size,
                              hipStream_t stream) {
    const float* x     = (const float*)d_in[0];
    const int*   ei    = (const int*)d_in[1];
    const float* agg_W = (const float*)d_in[2];
    const float* agg_b = (const float*)d_in[3];
    const float* W     = (const float*)d_in[4];
    const float* b     = (const float*)d_in[5];
    const float* gamma = (const float*)d_in[6];
    const float* beta  = (const float*)d_in[7];
    float*       out   = (float*)d_out;

    size_t out_bytes = (size_t)out_size * sizeof(float);

    if (n_in != 8)                       { hipMemsetAsync(d_out, 0x45, out_bytes, stream); return; }
    if (in_sizes[0] != N_NODES * D_FEAT) { hipMemsetAsync(d_out, 0x48, out_bytes, stream); return; }
    if (in_sizes[1] != 2 * N_EDGES)      { hipMemsetAsync(d_out, 0x49, out_bytes, stream); return; }
    if (out_size != N_NODES * D_FEAT)    { hipMemsetAsync(d_out, 0x47, out_bytes, stream); return; }

    // workspace layout (4-byte elements)
    int*   deg_cnt  = (int*)d_ws;                  // 50000
    int*   pos      = deg_cnt + N_NODES;           // 50000
    int*   edge_src = pos + N_NODES;               // 800000
    float* Wt2      = (float*)(edge_src + N_EDGES);// 256*128
    float* cvec     = Wt2 + 256 * 128;             // 128
    int*   bsum     = (int*)(cvec + 128);          // NBLK
    int*   boff     = bsum + NBLK;                 // NBLK
    size_t need_ws = ((size_t)N_NODES * 2 + N_EDGES + 256 * 128 + 128 + 2 * NBLK) * 4;
    if (ws_size < need_ws)               { hipMemsetAsync(d_out, 0x46, out_bytes, stream); return; }

    zero_kernel<<<(N_NODES + 255) / 256, 256, 0, stream>>>(deg_cnt, N_NODES);
    hist_kernel<<<(N_EDGES + 255) / 256, 256, 0, stream>>>(ei, deg_cnt);
    blocksum_kernel<<<NBLK, 256, 0, stream>>>(deg_cnt, bsum);
    scanblk_kernel<<<1, 256, 0, stream>>>(bsum, boff);
    scanpos_kernel<<<NBLK, 256, 0, stream>>>(deg_cnt, boff, pos);
    fill_kernel<<<(N_EDGES + 255) / 256, 256, 0, stream>>>(ei, pos, edge_src);
    wprep_kernel<<<128, 128, 0, stream>>>(agg_W, agg_b, W, b, Wt2, cvec);
    gsage_fused<<<(N_NODES + TM - 1) / TM, 256, 0, stream>>>(
        x, pos, deg_cnt, edge_src, Wt2, cvec, gamma, beta, out);
}

// Round 8
// 296.852 us; speedup vs baseline: 1.1308x; 1.1308x over previous
//
#include <hip/hip_runtime.h>

#define N_NODES 50000
#define N_EDGES 800000
#define D_FEAT 128
#define LN_EPS 1e-5f
#define TM 32          // nodes per block in gsage_main
#define KB 32          // K-chunk
#define APAD 36        // padded A-tile row stride (floats), keeps 16B alignment
#define NBLK 196       // ceil(N_NODES/256) scan blocks

// ---------------------------------------------------------------------------
// zero the degree counters (ws is poisoned 0xAA every call)
// ---------------------------------------------------------------------------
__global__ void zero_kernel(int* __restrict__ p, int n)
{
    int i = blockIdx.x * 256 + threadIdx.x;
    if (i < n) p[i] = 0;
}

// ---------------------------------------------------------------------------
// histogram of destination nodes
// ---------------------------------------------------------------------------
__global__ void hist_kernel(const int* __restrict__ ei, int* __restrict__ deg_cnt)
{
    int e = blockIdx.x * 256 + threadIdx.x;
    if (e >= N_EDGES) return;
    int dst = ei[N_EDGES + e];
    dst = (dst < 0) ? 0 : ((dst >= N_NODES) ? (N_NODES - 1) : dst);
    atomicAdd(&deg_cnt[dst], 1);
}

// ---------------------------------------------------------------------------
// scan phase 1: per-block (256-elem chunk) sum of deg_cnt -> bsum[block]
// ---------------------------------------------------------------------------
__global__ void blocksum_kernel(const int* __restrict__ deg_cnt, int* __restrict__ bsum)
{
    __shared__ int ws[4];
    int b = blockIdx.x, t = threadIdx.x;
    int i = b * 256 + t;
    int v = (i < N_NODES) ? deg_cnt[i] : 0;
    #pragma unroll
    for (int off = 1; off < 64; off <<= 1) v += __shfl_xor(v, off, 64);
    if ((t & 63) == 0) ws[t >> 6] = v;
    __syncthreads();
    if (t == 0) bsum[b] = ws[0] + ws[1] + ws[2] + ws[3];
}

// ---------------------------------------------------------------------------
// scan phase 2: exclusive scan of the 196 block sums (single small block)
// ---------------------------------------------------------------------------
__global__ void scanblk_kernel(const int* __restrict__ bsum, int* __restrict__ boff)
{
    __shared__ int s[256];
    int t = threadIdx.x;
    int v = (t < NBLK) ? bsum[t] : 0;
    s[t] = v;
    __syncthreads();
    for (int off = 1; off < 256; off <<= 1) {
        int u = (t >= off) ? s[t - off] : 0;
        __syncthreads();
        s[t] += u;
        __syncthreads();
    }
    if (t < NBLK) boff[t] = s[t] - v;   // exclusive
}

// ---------------------------------------------------------------------------
// scan phase 3: block-local exclusive scan + block offset -> pos
// ---------------------------------------------------------------------------
__global__ void scanpos_kernel(const int* __restrict__ deg_cnt,
                               const int* __restrict__ boff,
                               int* __restrict__ pos)
{
    __shared__ int s[256];
    int b = blockIdx.x, t = threadIdx.x;
    int i = b * 256 + t;
    int v = (i < N_NODES) ? deg_cnt[i] : 0;
    s[t] = v;
    __syncthreads();
    for (int off = 1; off < 256; off <<= 1) {
        int u = (t >= off) ? s[t - off] : 0;
        __syncthreads();
        s[t] += u;
        __syncthreads();
    }
    if (i < N_NODES) pos[i] = boff[b] + s[t] - v;   // exclusive global
}

// ---------------------------------------------------------------------------
// bucket fill: edge_src[slot] = src, slot = pos[dst]++  (after this, pos = end)
// ---------------------------------------------------------------------------
__global__ void fill_kernel(const int* __restrict__ ei, int* __restrict__ pos,
                            int* __restrict__ edge_src)
{
    int e = blockIdx.x * 256 + threadIdx.x;
    if (e >= N_EDGES) return;
    int src = ei[e];
    int dst = ei[N_EDGES + e];
    src = (src < 0) ? 0 : ((src >= N_NODES) ? (N_NODES - 1) : src);
    dst = (dst < 0) ? 0 : ((dst >= N_NODES) ? (N_NODES - 1) : dst);
    int slot = atomicAdd(&pos[dst], 1);
    edge_src[slot] = src;
}

// ---------------------------------------------------------------------------
// gather: one 64-lane wave per node, 2 edges per iteration (half-wave per
// edge, float4 per lane). agg mean written into d_out (scratch).
// ---------------------------------------------------------------------------
__global__ void gather_kernel(const float* __restrict__ x,
                              const int* __restrict__ pos,      // = end after fill
                              const int* __restrict__ deg_cnt,
                              const int* __restrict__ edge_src,
                              float* __restrict__ agg)          // d_out scratch
{
    int tid  = threadIdx.x;
    int node = blockIdx.x * 4 + (tid >> 6);
    int lane = tid & 63;
    int half = lane >> 5;
    int sub  = lane & 31;
    if (node >= N_NODES) return;

    int end   = pos[node];
    int dcnt  = deg_cnt[node];
    int start = end - dcnt;

    float4 acc = make_float4(0.f, 0.f, 0.f, 0.f);
    for (int b = start; b < end; b += 64) {
        int nb = end - b; if (nb > 64) nb = 64;
        int sid = (b + lane < end) ? edge_src[b + lane] : 0;
        for (int j = 0; j < nb; j += 2) {
            int eidx = j + half;                 // half-wave per edge
            int s = __shfl(sid, eidx, 64);
            if (eidx < nb) {
                const float4 v = *(const float4*)(x + (size_t)s * D_FEAT + sub * 4);
                acc.x += v.x; acc.y += v.y; acc.z += v.z; acc.w += v.w;
            }
        }
    }
    // cross-half reduce (lane ^ 32): both halves hold the same feature slice
    acc.x += __shfl_xor(acc.x, 32, 64);
    acc.y += __shfl_xor(acc.y, 32, 64);
    acc.z += __shfl_xor(acc.z, 32, 64);
    acc.w += __shfl_xor(acc.w, 32, 64);
    if (half == 0) {
        float inv = 1.0f / (float)((dcnt > 1) ? dcnt : 1);
        float4 m;
        m.x = acc.x * inv; m.y = acc.y * inv;
        m.z = acc.z * inv; m.w = acc.w * inv;
        *(float4*)(agg + (size_t)node * D_FEAT + sub * 4) = m;
    }
}

// ---------------------------------------------------------------------------
// weight prep.  Wt2 layout [k][n], k<128 -> W1 (verbatim copy of W's first
// half); k>=128 -> M = agg_W @ W2.  cvec[n] = b[n] + sum_j agg_b[j]*W2[j][n].
// ---------------------------------------------------------------------------
__global__ void wprep_kernel(const float* __restrict__ agg_W,
                             const float* __restrict__ agg_b,
                             const float* __restrict__ W,
                             const float* __restrict__ b,
                             float* __restrict__ Wt2,
                             float* __restrict__ cvec)
{
    int t = blockIdx.x;    // 0..127
    int n = threadIdx.x;   // 0..127

    Wt2[t * 128 + n] = W[t * 128 + n];            // W1 half, already [k][n]

    float m = 0.0f;
    for (int j = 0; j < 128; ++j)
        m += agg_W[t * 128 + j] * W[(128 + j) * 128 + n];
    Wt2[(128 + t) * 128 + n] = m;

    if (t == 0) {
        float s = b[n];
        for (int j = 0; j < 128; ++j)
            s += agg_b[j] * W[(128 + j) * 128 + n];
        cvec[n] = s;
    }
}

// ---------------------------------------------------------------------------
// fused GEMM (A=[x|agg] @ Wt2^T + c) -> ReLU -> LayerNorm -> out (fp32).
// 256 threads, 32 nodes/block; K=256 chunked by 32; A + W chunks in LDS.
// Thread (tx=tid&31, ty=tid>>5) owns 4 nodes (ty*4..) x 4 cols (tx*4..).
// NOTE: reads agg rows from d_out and later overwrites the same rows; safe
// because each block only touches its own 32 nodes and all reads precede
// the epilogue stores.
// ---------------------------------------------------------------------------
__global__ __launch_bounds__(256) void gsage_main(
        const float* __restrict__ x,
        const float* __restrict__ agg,      // aliases `out`
        const float* __restrict__ Wt2,
        const float* __restrict__ cvec,
        const float* __restrict__ gamma,
        const float* __restrict__ beta,
        float* __restrict__ out)
{
    __shared__ float A[TM][APAD];     // 32 x 36 floats
    __shared__ float Wc[KB * 128];    // 32 x 128 floats

    int tid   = threadIdx.x;
    int tx    = tid & 31;
    int ty    = tid >> 5;
    int node0 = blockIdx.x * TM;

    float acc[4][4];
    #pragma unroll
    for (int i = 0; i < 4; ++i)
        #pragma unroll
        for (int j = 0; j < 4; ++j) acc[i][j] = 0.0f;

    for (int c = 0; c < 256 / KB; ++c) {
        int k0 = c * KB;
        // ---- stage A chunk: node = tid>>3, kk = (tid&7)*4 ----
        {
            int r  = tid >> 3;
            int kk = (tid & 7) * 4;
            int k  = k0 + kk;
            int node = node0 + r;
            float4 v = make_float4(0.f, 0.f, 0.f, 0.f);
            if (node < N_NODES) {
                const float* src = (k < 128)
                    ? (x   + (size_t)node * D_FEAT + k)
                    : (agg + (size_t)node * D_FEAT + (k - 128));
                v = *(const float4*)src;
            }
            *(float4*)&A[r][kk] = v;
        }
        // ---- stage W chunk: rows k0..k0+31 of Wt2, 16 KB contiguous ----
        {
            const float4* src = (const float4*)(Wt2 + k0 * 128);
            float4* dstp = (float4*)Wc;
            #pragma unroll
            for (int i = 0; i < 4; ++i)
                dstp[i * 256 + tid] = src[i * 256 + tid];
        }
        __syncthreads();

        // ---- inner product ----
        #pragma unroll 8
        for (int kk = 0; kk < KB; ++kk) {
            float a0 = A[ty * 4 + 0][kk];
            float a1 = A[ty * 4 + 1][kk];
            float a2 = A[ty * 4 + 2][kk];
            float a3 = A[ty * 4 + 3][kk];
            float4 w = *(const float4*)&Wc[kk * 128 + tx * 4];
            acc[0][0] += a0 * w.x; acc[0][1] += a0 * w.y; acc[0][2] += a0 * w.z; acc[0][3] += a0 * w.w;
            acc[1][0] += a1 * w.x; acc[1][1] += a1 * w.y; acc[1][2] += a1 * w.z; acc[1][3] += a1 * w.w;
            acc[2][0] += a2 * w.x; acc[2][1] += a2 * w.y; acc[2][2] += a2 * w.z; acc[2][3] += a2 * w.w;
            acc[3][0] += a3 * w.x; acc[3][1] += a3 * w.y; acc[3][2] += a3 * w.z; acc[3][3] += a3 * w.w;
        }
        __syncthreads();
    }

    // ---- epilogue: +c, ReLU, LayerNorm over 128 cols (32 tx lanes) ----
    float4 cv = *(const float4*)(cvec  + tx * 4);
    float4 gv = *(const float4*)(gamma + tx * 4);
    float4 bv = *(const float4*)(beta  + tx * 4);

    #pragma unroll
    for (int i = 0; i < 4; ++i) {
        float v0 = acc[i][0] + cv.x; v0 = (v0 > 0.f) ? v0 : 0.f;
        float v1 = acc[i][1] + cv.y; v1 = (v1 > 0.f) ? v1 : 0.f;
        float v2 = acc[i][2] + cv.z; v2 = (v2 > 0.f) ? v2 : 0.f;
        float v3 = acc[i][3] + cv.w; v3 = (v3 > 0.f) ? v3 : 0.f;
        float s1 = v0 + v1 + v2 + v3;
        float s2 = v0*v0 + v1*v1 + v2*v2 + v3*v3;
        #pragma unroll
        for (int m = 1; m < 32; m <<= 1) {
            s1 += __shfl_xor(s1, m, 64);
            s2 += __shfl_xor(s2, m, 64);
        }
        float mu  = s1 * (1.0f / 128.0f);
        float var = s2 * (1.0f / 128.0f) - mu * mu;
        float rstd = rsqrtf(var + LN_EPS);
        int node = node0 + ty * 4 + i;
        if (node < N_NODES) {
            float4 o;
            o.x = (v0 - mu) * rstd * gv.x + bv.x;
            o.y = (v1 - mu) * rstd * gv.y + bv.y;
            o.z = (v2 - mu) * rstd * gv.z + bv.z;
            o.w = (v3 - mu) * rstd * gv.w + bv.w;
            *(float4*)(out + (size_t)node * D_FEAT + tx * 4) = o;
        }
    }
}

// ---------------------------------------------------------------------------
extern "C" void kernel_launch(void* const* d_in, const int* in_sizes, int n_in,
                              void* d_out, int out_size, void* d_ws, size_t ws_size,
                              hipStream_t stream) {
    const float* x     = (const float*)d_in[0];
    const int*   ei    = (const int*)d_in[1];
    const float* agg_W = (const float*)d_in[2];
    const float* agg_b = (const float*)d_in[3];
    const float* W     = (const float*)d_in[4];
    const float* b     = (const float*)d_in[5];
    const float* gamma = (const float*)d_in[6];
    const float* beta  = (const float*)d_in[7];
    float*       out   = (float*)d_out;

    size_t out_bytes = (size_t)out_size * sizeof(float);

    if (n_in != 8)                       { hipMemsetAsync(d_out, 0x45, out_bytes, stream); return; }
    if (in_sizes[0] != N_NODES * D_FEAT) { hipMemsetAsync(d_out, 0x48, out_bytes, stream); return; }
    if (in_sizes[1] != 2 * N_EDGES)      { hipMemsetAsync(d_out, 0x49, out_bytes, stream); return; }
    if (out_size != N_NODES * D_FEAT)    { hipMemsetAsync(d_out, 0x47, out_bytes, stream); return; }

    // workspace layout (4-byte elements)
    int*   deg_cnt  = (int*)d_ws;                  // 50000
    int*   pos      = deg_cnt + N_NODES;           // 50000
    int*   edge_src = pos + N_NODES;               // 800000
    float* Wt2      = (float*)(edge_src + N_EDGES);// 256*128
    float* cvec     = Wt2 + 256 * 128;             // 128
    int*   bsum     = (int*)(cvec + 128);          // NBLK
    int*   boff     = bsum + NBLK;                 // NBLK
    size_t need_ws = ((size_t)N_NODES * 2 + N_EDGES + 256 * 128 + 128 + 2 * NBLK) * 4;
    if (ws_size < need_ws)               { hipMemsetAsync(d_out, 0x46, out_bytes, stream); return; }

    zero_kernel<<<(N_NODES + 255) / 256, 256, 0, stream>>>(deg_cnt, N_NODES);
    hist_kernel<<<(N_EDGES + 255) / 256, 256, 0, stream>>>(ei, deg_cnt);
    blocksum_kernel<<<NBLK, 256, 0, stream>>>(deg_cnt, bsum);
    scanblk_kernel<<<1, 256, 0, stream>>>(bsum, boff);
    scanpos_kernel<<<NBLK, 256, 0, stream>>>(deg_cnt, boff, pos);
    fill_kernel<<<(N_EDGES + 255) / 256, 256, 0, stream>>>(ei, pos, edge_src);
    wprep_kernel<<<128, 128, 0, stream>>>(agg_W, agg_b, W, b, Wt2, cvec);
    gather_kernel<<<(N_NODES + 3) / 4, 256, 0, stream>>>(x, pos, deg_cnt, edge_src, out);
    gsage_main<<<(N_NODES + TM - 1) / TM, 256, 0, stream>>>(
        x, out, Wt2, cvec, gamma, beta, out);
}

// Round 9
// 286.888 us; speedup vs baseline: 1.1701x; 1.0347x over previous
//
#include <hip/hip_runtime.h>

#define N_NODES 50000
#define N_EDGES 800000
#define D_FEAT 128
#define LN_EPS 1e-5f
#define TM 64          // nodes per block in gsage_main
#define KB 32          // K-chunk
#define APAD 36        // padded A-tile row stride (floats)
#define NBLK 196       // ceil(N_NODES/256) scan blocks

__device__ __forceinline__ unsigned short f2bf(float f) {
    union { float f; unsigned int i; } v; v.f = f;
    unsigned int x = v.i;
    unsigned int lsb = (x >> 16) & 1u;
    x += 0x7fffu + lsb;          // RNE
    return (unsigned short)(x >> 16);
}
__device__ __forceinline__ float bflo(unsigned int u) {
    union { unsigned int i; float f; } v; v.i = u << 16; return v.f;
}
__device__ __forceinline__ float bfhi(unsigned int u) {
    union { unsigned int i; float f; } v; v.i = u & 0xffff0000u; return v.f;
}

// ---------------------------------------------------------------------------
__global__ void zero_kernel(int* __restrict__ p, int n)
{
    int i = blockIdx.x * 256 + threadIdx.x;
    if (i < n) p[i] = 0;
}

// ---------------------------------------------------------------------------
__global__ void hist_kernel(const int* __restrict__ ei, int* __restrict__ deg_cnt)
{
    int e = blockIdx.x * 256 + threadIdx.x;
    if (e >= N_EDGES) return;
    int dst = ei[N_EDGES + e];
    dst = (dst < 0) ? 0 : ((dst >= N_NODES) ? (N_NODES - 1) : dst);
    atomicAdd(&deg_cnt[dst], 1);
}

// ---------------------------------------------------------------------------
__global__ void blocksum_kernel(const int* __restrict__ deg_cnt, int* __restrict__ bsum)
{
    __shared__ int ws[4];
    int b = blockIdx.x, t = threadIdx.x;
    int i = b * 256 + t;
    int v = (i < N_NODES) ? deg_cnt[i] : 0;
    #pragma unroll
    for (int off = 1; off < 64; off <<= 1) v += __shfl_xor(v, off, 64);
    if ((t & 63) == 0) ws[t >> 6] = v;
    __syncthreads();
    if (t == 0) bsum[b] = ws[0] + ws[1] + ws[2] + ws[3];
}

// ---------------------------------------------------------------------------
__global__ void scanblk_kernel(const int* __restrict__ bsum, int* __restrict__ boff)
{
    __shared__ int s[256];
    int t = threadIdx.x;
    int v = (t < NBLK) ? bsum[t] : 0;
    s[t] = v;
    __syncthreads();
    for (int off = 1; off < 256; off <<= 1) {
        int u = (t >= off) ? s[t - off] : 0;
        __syncthreads();
        s[t] += u;
        __syncthreads();
    }
    if (t < NBLK) boff[t] = s[t] - v;   // exclusive
}

// ---------------------------------------------------------------------------
__global__ void scanpos_kernel(const int* __restrict__ deg_cnt,
                               const int* __restrict__ boff,
                               int* __restrict__ pos)
{
    __shared__ int s[256];
    int b = blockIdx.x, t = threadIdx.x;
    int i = b * 256 + t;
    int v = (i < N_NODES) ? deg_cnt[i] : 0;
    s[t] = v;
    __syncthreads();
    for (int off = 1; off < 256; off <<= 1) {
        int u = (t >= off) ? s[t - off] : 0;
        __syncthreads();
        s[t] += u;
        __syncthreads();
    }
    if (i < N_NODES) pos[i] = boff[b] + s[t] - v;   // exclusive global
}

// ---------------------------------------------------------------------------
__global__ void fill_kernel(const int* __restrict__ ei, int* __restrict__ pos,
                            int* __restrict__ edge_src)
{
    int e = blockIdx.x * 256 + threadIdx.x;
    if (e >= N_EDGES) return;
    int src = ei[e];
    int dst = ei[N_EDGES + e];
    src = (src < 0) ? 0 : ((src >= N_NODES) ? (N_NODES - 1) : src);
    dst = (dst < 0) ? 0 : ((dst >= N_NODES) ? (N_NODES - 1) : dst);
    int slot = atomicAdd(&pos[dst], 1);
    edge_src[slot] = src;
}

// ---------------------------------------------------------------------------
// x (fp32) -> xh (bf16 packed, 2 per uint). 8 floats per thread.
// ---------------------------------------------------------------------------
__global__ void cvt_kernel(const float* __restrict__ x, unsigned int* __restrict__ xh)
{
    int i = blockIdx.x * 256 + threadIdx.x;          // 800000 threads
    const float4 a = *(const float4*)(x + (size_t)i * 8);
    const float4 b = *(const float4*)(x + (size_t)i * 8 + 4);
    uint4 o;
    o.x = ((unsigned)f2bf(a.y) << 16) | f2bf(a.x);
    o.y = ((unsigned)f2bf(a.w) << 16) | f2bf(a.z);
    o.z = ((unsigned)f2bf(b.y) << 16) | f2bf(b.x);
    o.w = ((unsigned)f2bf(b.w) << 16) | f2bf(b.z);
    *(uint4*)(xh + (size_t)i * 4) = o;
}

// ---------------------------------------------------------------------------
// gather: one wave per node, 4 edges per iteration (quarter-wave per edge,
// uint4 = 8 bf16 feats per lane). agg mean (fp32) written into d_out scratch.
// ---------------------------------------------------------------------------
__global__ void gather_kernel(const uint4* __restrict__ xh,   // 16 uint4 per row
                              const int* __restrict__ pos,    // = end after fill
                              const int* __restrict__ deg_cnt,
                              const int* __restrict__ edge_src,
                              float* __restrict__ agg)        // d_out scratch
{
    int tid  = threadIdx.x;
    int node = blockIdx.x * 4 + (tid >> 6);
    int lane = tid & 63;
    int quarter = lane >> 4;     // 0..3  (edge slot within iteration)
    int sub     = lane & 15;     // 0..15 (uint4 within row)
    if (node >= N_NODES) return;

    int end   = pos[node];
    int dcnt  = deg_cnt[node];
    int start = end - dcnt;

    float a0 = 0.f, a1 = 0.f, a2 = 0.f, a3 = 0.f,
          a4 = 0.f, a5 = 0.f, a6 = 0.f, a7 = 0.f;

    for (int b = start; b < end; b += 64) {
        int nb = end - b; if (nb > 64) nb = 64;
        int sid = (b + lane < end) ? edge_src[b + lane] : 0;
        for (int j = 0; j < nb; j += 4) {
            int eidx = j + quarter;
            int s = __shfl(sid, eidx, 64);
            if (eidx < nb) {
                const uint4 v = xh[(size_t)s * 16 + sub];
                a0 += bflo(v.x); a1 += bfhi(v.x);
                a2 += bflo(v.y); a3 += bfhi(v.y);
                a4 += bflo(v.z); a5 += bfhi(v.z);
                a6 += bflo(v.w); a7 += bfhi(v.w);
            }
        }
    }
    // reduce across the 4 quarters (lane ^ 16, lane ^ 32)
    #pragma unroll
    for (int m = 16; m <= 32; m <<= 1) {
        a0 += __shfl_xor(a0, m, 64); a1 += __shfl_xor(a1, m, 64);
        a2 += __shfl_xor(a2, m, 64); a3 += __shfl_xor(a3, m, 64);
        a4 += __shfl_xor(a4, m, 64); a5 += __shfl_xor(a5, m, 64);
        a6 += __shfl_xor(a6, m, 64); a7 += __shfl_xor(a7, m, 64);
    }
    if (quarter == 0) {
        float inv = 1.0f / (float)((dcnt > 1) ? dcnt : 1);
        float4 m0, m1;
        m0.x = a0 * inv; m0.y = a1 * inv; m0.z = a2 * inv; m0.w = a3 * inv;
        m1.x = a4 * inv; m1.y = a5 * inv; m1.z = a6 * inv; m1.w = a7 * inv;
        float* dst = agg + (size_t)node * D_FEAT + sub * 8;
        *(float4*)dst       = m0;
        *(float4*)(dst + 4) = m1;
    }
}

// ---------------------------------------------------------------------------
// weight prep.  Wt2 layout [k][n], k<128 -> W1; k>=128 -> M = agg_W @ W2.
// cvec[n] = b[n] + sum_j agg_b[j]*W2[j][n].
// ---------------------------------------------------------------------------
__global__ void wprep_kernel(const float* __restrict__ agg_W,
                             const float* __restrict__ agg_b,
                             const float* __restrict__ W,
                             const float* __restrict__ b,
                             float* __restrict__ Wt2,
                             float* __restrict__ cvec)
{
    int t = blockIdx.x;    // 0..127
    int n = threadIdx.x;   // 0..127

    Wt2[t * 128 + n] = W[t * 128 + n];            // W1 half, already [k][n]

    float m = 0.0f;
    for (int j = 0; j < 128; ++j)
        m += agg_W[t * 128 + j] * W[(128 + j) * 128 + n];
    Wt2[(128 + t) * 128 + n] = m;

    if (t == 0) {
        float s = b[n];
        for (int j = 0; j < 128; ++j)
            s += agg_b[j] * W[(128 + j) * 128 + n];
        cvec[n] = s;
    }
}

// ---------------------------------------------------------------------------
// fused GEMM (A=[x|agg] @ Wt2^T + c) -> ReLU -> LayerNorm -> out (fp32).
// 256 threads, TM=64 nodes/block; thread (tx=tid&15, ty=tid>>4) owns
// 4 nodes x 8 cols (32 accs).  Per k-step: 4 ds_read_b32 + 2 ds_read_b128
// vs 32 FMAs -> VALU-bound.
// agg aliases out: each block reads only its own nodes' agg before writing.
// ---------------------------------------------------------------------------
__global__ __launch_bounds__(256) void gsage_main(
        const float* __restrict__ x,
        const float* __restrict__ agg,      // aliases `out`
        const float* __restrict__ Wt2,
        const float* __restrict__ cvec,
        const float* __restrict__ gamma,
        const float* __restrict__ beta,
        float* __restrict__ out)
{
    __shared__ float A[TM][APAD];     // 64 x 36 floats = 9.2 KB
    __shared__ float Wc[KB * 128];    // 16 KB

    int tid   = threadIdx.x;
    int tx    = tid & 15;             // 16 col groups x 8 cols
    int ty    = tid >> 4;             // 16 row groups x 4 nodes
    int node0 = blockIdx.x * TM;

    float acc[4][8];
    #pragma unroll
    for (int i = 0; i < 4; ++i)
        #pragma unroll
        for (int j = 0; j < 8; ++j) acc[i][j] = 0.0f;

    for (int c = 0; c < 256 / KB; ++c) {
        int k0 = c * KB;
        // ---- stage A chunk: 64 rows x 32 k (512 float4, 2 per thread) ----
        #pragma unroll
        for (int it = 0; it < 2; ++it) {
            int idx = it * 256 + tid;
            int r  = idx >> 3;
            int kk = (idx & 7) * 4;
            int k  = k0 + kk;
            int node = node0 + r;
            float4 v = make_float4(0.f, 0.f, 0.f, 0.f);
            if (node < N_NODES) {
                const float* src = (k < 128)
                    ? (x   + (size_t)node * D_FEAT + k)
                    : (agg + (size_t)node * D_FEAT + (k - 128));
                v = *(const float4*)src;
            }
            *(float4*)&A[r][kk] = v;
        }
        // ---- stage W chunk (16 KB contiguous) ----
        {
            const float4* src = (const float4*)(Wt2 + k0 * 128);
            float4* dstp = (float4*)Wc;
            #pragma unroll
            for (int i = 0; i < 4; ++i)
                dstp[i * 256 + tid] = src[i * 256 + tid];
        }
        __syncthreads();

        // ---- inner product ----
        #pragma unroll 8
        for (int kk = 0; kk < KB; ++kk) {
            float a0 = A[ty * 4 + 0][kk];
            float a1 = A[ty * 4 + 1][kk];
            float a2 = A[ty * 4 + 2][kk];
            float a3 = A[ty * 4 + 3][kk];
            float4 w0 = *(const float4*)&Wc[kk * 128 + tx * 8];
            float4 w1 = *(const float4*)&Wc[kk * 128 + tx * 8 + 4];
            acc[0][0] += a0*w0.x; acc[0][1] += a0*w0.y; acc[0][2] += a0*w0.z; acc[0][3] += a0*w0.w;
            acc[0][4] += a0*w1.x; acc[0][5] += a0*w1.y; acc[0][6] += a0*w1.z; acc[0][7] += a0*w1.w;
            acc[1][0] += a1*w0.x; acc[1][1] += a1*w0.y; acc[1][2] += a1*w0.z; acc[1][3] += a1*w0.w;
            acc[1][4] += a1*w1.x; acc[1][5] += a1*w1.y; acc[1][6] += a1*w1.z; acc[1][7] += a1*w1.w;
            acc[2][0] += a2*w0.x; acc[2][1] += a2*w0.y; acc[2][2] += a2*w0.z; acc[2][3] += a2*w0.w;
            acc[2][4] += a2*w1.x; acc[2][5] += a2*w1.y; acc[2][6] += a2*w1.z; acc[2][7] += a2*w1.w;
            acc[3][0] += a3*w0.x; acc[3][1] += a3*w0.y; acc[3][2] += a3*w0.z; acc[3][3] += a3*w0.w;
            acc[3][4] += a3*w1.x; acc[3][5] += a3*w1.y; acc[3][6] += a3*w1.z; acc[3][7] += a3*w1.w;
        }
        __syncthreads();
    }

    // ---- epilogue: +c, ReLU, LayerNorm over 128 cols (16 tx lanes x 8) ----
    float4 cv0 = *(const float4*)(cvec  + tx * 8), cv1 = *(const float4*)(cvec  + tx * 8 + 4);
    float4 gv0 = *(const float4*)(gamma + tx * 8), gv1 = *(const float4*)(gamma + tx * 8 + 4);
    float4 bv0 = *(const float4*)(beta  + tx * 8), bv1 = *(const float4*)(beta  + tx * 8 + 4);
    float cc[8] = {cv0.x,cv0.y,cv0.z,cv0.w,cv1.x,cv1.y,cv1.z,cv1.w};
    float gg[8] = {gv0.x,gv0.y,gv0.z,gv0.w,gv1.x,gv1.y,gv1.z,gv1.w};
    float bb[8] = {bv0.x,bv0.y,bv0.z,bv0.w,bv1.x,bv1.y,bv1.z,bv1.w};

    #pragma unroll
    for (int i = 0; i < 4; ++i) {
        float v[8]; float s1 = 0.f, s2 = 0.f;
        #pragma unroll
        for (int j = 0; j < 8; ++j) {
            float t = acc[i][j] + cc[j];
            t = (t > 0.f) ? t : 0.f;
            v[j] = t; s1 += t; s2 += t * t;
        }
        #pragma unroll
        for (int m = 1; m < 16; m <<= 1) {   // reduce across 16 tx lanes
            s1 += __shfl_xor(s1, m, 64);
            s2 += __shfl_xor(s2, m, 64);
        }
        float mu   = s1 * (1.0f / 128.0f);
        float var  = s2 * (1.0f / 128.0f) - mu * mu;
        float rstd = rsqrtf(var + LN_EPS);
        int node = node0 + ty * 4 + i;
        if (node < N_NODES) {
            float4 o0, o1;
            o0.x = (v[0]-mu)*rstd*gg[0]+bb[0]; o0.y = (v[1]-mu)*rstd*gg[1]+bb[1];
            o0.z = (v[2]-mu)*rstd*gg[2]+bb[2]; o0.w = (v[3]-mu)*rstd*gg[3]+bb[3];
            o1.x = (v[4]-mu)*rstd*gg[4]+bb[4]; o1.y = (v[5]-mu)*rstd*gg[5]+bb[5];
            o1.z = (v[6]-mu)*rstd*gg[6]+bb[6]; o1.w = (v[7]-mu)*rstd*gg[7]+bb[7];
            float* dst = out + (size_t)node * D_FEAT + tx * 8;
            *(float4*)dst       = o0;
            *(float4*)(dst + 4) = o1;
        }
    }
}

// ---------------------------------------------------------------------------
extern "C" void kernel_launch(void* const* d_in, const int* in_sizes, int n_in,
                              void* d_out, int out_size, void* d_ws, size_t ws_size,
                              hipStream_t stream) {
    const float* x     = (const float*)d_in[0];
    const int*   ei    = (const int*)d_in[1];
    const float* agg_W = (const float*)d_in[2];
    const float* agg_b = (const float*)d_in[3];
    const float* W     = (const float*)d_in[4];
    const float* b     = (const float*)d_in[5];
    const float* gamma = (const float*)d_in[6];
    const float* beta  = (const float*)d_in[7];
    float*       out   = (float*)d_out;

    size_t out_bytes = (size_t)out_size * sizeof(float);

    if (n_in != 8)                       { hipMemsetAsync(d_out, 0x45, out_bytes, stream); return; }
    if (in_sizes[0] != N_NODES * D_FEAT) { hipMemsetAsync(d_out, 0x48, out_bytes, stream); return; }
    if (in_sizes[1] != 2 * N_EDGES)      { hipMemsetAsync(d_out, 0x49, out_bytes, stream); return; }
    if (out_size != N_NODES * D_FEAT)    { hipMemsetAsync(d_out, 0x47, out_bytes, stream); return; }

    // workspace layout (4-byte elements)
    int*   deg_cnt  = (int*)d_ws;                  // 50000
    int*   pos      = deg_cnt + N_NODES;           // 50000
    int*   edge_src = pos + N_NODES;               // 800000
    float* Wt2      = (float*)(edge_src + N_EDGES);// 256*128
    float* cvec     = Wt2 + 256 * 128;             // 128
    int*   bsum     = (int*)(cvec + 128);          // NBLK
    int*   boff     = bsum + NBLK;                 // NBLK
    unsigned int* xh = (unsigned int*)(boff + NBLK); // 50000*64 uints (bf16 x)
    size_t need_ws = ((size_t)N_NODES * 2 + N_EDGES + 256 * 128 + 128 + 2 * NBLK
                      + (size_t)N_NODES * 64) * 4;
    if (ws_size < need_ws)               { hipMemsetAsync(d_out, 0x46, out_bytes, stream); return; }

    zero_kernel<<<(N_NODES + 255) / 256, 256, 0, stream>>>(deg_cnt, N_NODES);
    hist_kernel<<<(N_EDGES + 255) / 256, 256, 0, stream>>>(ei, deg_cnt);
    blocksum_kernel<<<NBLK, 256, 0, stream>>>(deg_cnt, bsum);
    scanblk_kernel<<<1, 256, 0, stream>>>(bsum, boff);
    scanpos_kernel<<<NBLK, 256, 0, stream>>>(deg_cnt, boff, pos);
    fill_kernel<<<(N_EDGES + 255) / 256, 256, 0, stream>>>(ei, pos, edge_src);
    wprep_kernel<<<128, 128, 0, stream>>>(agg_W, agg_b, W, b, Wt2, cvec);
    cvt_kernel<<<(N_NODES * D_FEAT / 8 + 255) / 256, 256, 0, stream>>>(x, xh);
    gather_kernel<<<(N_NODES + 3) / 4, 256, 0, stream>>>(
        (const uint4*)xh, pos, deg_cnt, edge_src, out);
    gsage_main<<<(N_NODES + TM - 1) / TM, 256, 0, stream>>>(
        x, out, Wt2, cvec, gamma, beta, out);
}

// Round 10
// 286.415 us; speedup vs baseline: 1.1720x; 1.0017x over previous
//
#include <hip/hip_runtime.h>

#define N_NODES 50000
#define N_EDGES 800000
#define D_FEAT 128
#define LN_EPS 1e-5f
#define TM 64          // nodes per block in gsage_main
#define KB 32          // K-chunk
#define APAD 36        // padded A-tile row stride (floats)
#define NBLK 196       // ceil(N_NODES/256) scan blocks

__device__ __forceinline__ unsigned short f2bf(float f) {
    union { float f; unsigned int i; } v; v.f = f;
    unsigned int x = v.i;
    unsigned int lsb = (x >> 16) & 1u;
    x += 0x7fffu + lsb;          // RNE
    return (unsigned short)(x >> 16);
}
__device__ __forceinline__ float bflo(unsigned int u) {
    union { unsigned int i; float f; } v; v.i = u << 16; return v.f;
}
__device__ __forceinline__ float bfhi(unsigned int u) {
    union { unsigned int i; float f; } v; v.i = u & 0xffff0000u; return v.f;
}

// ---------------------------------------------------------------------------
__global__ void hist_kernel(const int* __restrict__ ei, int* __restrict__ deg_cnt)
{
    int e = blockIdx.x * 256 + threadIdx.x;
    if (e >= N_EDGES) return;
    int dst = ei[N_EDGES + e];
    dst = (dst < 0) ? 0 : ((dst >= N_NODES) ? (N_NODES - 1) : dst);
    atomicAdd(&deg_cnt[dst], 1);
}

// ---------------------------------------------------------------------------
__global__ void blocksum_kernel(const int* __restrict__ deg_cnt, int* __restrict__ bsum)
{
    __shared__ int ws[4];
    int b = blockIdx.x, t = threadIdx.x;
    int i = b * 256 + t;
    int v = (i < N_NODES) ? deg_cnt[i] : 0;
    #pragma unroll
    for (int off = 1; off < 64; off <<= 1) v += __shfl_xor(v, off, 64);
    if ((t & 63) == 0) ws[t >> 6] = v;
    __syncthreads();
    if (t == 0) bsum[b] = ws[0] + ws[1] + ws[2] + ws[3];
}

// ---------------------------------------------------------------------------
__global__ void scanblk_kernel(const int* __restrict__ bsum, int* __restrict__ boff)
{
    __shared__ int s[256];
    int t = threadIdx.x;
    int v = (t < NBLK) ? bsum[t] : 0;
    s[t] = v;
    __syncthreads();
    for (int off = 1; off < 256; off <<= 1) {
        int u = (t >= off) ? s[t - off] : 0;
        __syncthreads();
        s[t] += u;
        __syncthreads();
    }
    if (t < NBLK) boff[t] = s[t] - v;   // exclusive
}

// ---------------------------------------------------------------------------
__global__ void scanpos_kernel(const int* __restrict__ deg_cnt,
                               const int* __restrict__ boff,
                               int* __restrict__ pos)
{
    __shared__ int s[256];
    int b = blockIdx.x, t = threadIdx.x;
    int i = b * 256 + t;
    int v = (i < N_NODES) ? deg_cnt[i] : 0;
    s[t] = v;
    __syncthreads();
    for (int off = 1; off < 256; off <<= 1) {
        int u = (t >= off) ? s[t - off] : 0;
        __syncthreads();
        s[t] += u;
        __syncthreads();
    }
    if (i < N_NODES) pos[i] = boff[b] + s[t] - v;   // exclusive global
}

// ---------------------------------------------------------------------------
__global__ void fill_kernel(const int* __restrict__ ei, int* __restrict__ pos,
                            int* __restrict__ edge_src)
{
    int e = blockIdx.x * 256 + threadIdx.x;
    if (e >= N_EDGES) return;
    int src = ei[e];
    int dst = ei[N_EDGES + e];
    src = (src < 0) ? 0 : ((src >= N_NODES) ? (N_NODES - 1) : src);
    dst = (dst < 0) ? 0 : ((dst >= N_NODES) ? (N_NODES - 1) : dst);
    int slot = atomicAdd(&pos[dst], 1);
    edge_src[slot] = src;
}

// ---------------------------------------------------------------------------
// x (fp32) -> xh (bf16 packed, 2 per uint). 8 floats per thread.
// ---------------------------------------------------------------------------
__global__ void cvt_kernel(const float* __restrict__ x, unsigned int* __restrict__ xh)
{
    int i = blockIdx.x * 256 + threadIdx.x;          // 800000 threads
    const float4 a = *(const float4*)(x + (size_t)i * 8);
    const float4 b = *(const float4*)(x + (size_t)i * 8 + 4);
    uint4 o;
    o.x = ((unsigned)f2bf(a.y) << 16) | f2bf(a.x);
    o.y = ((unsigned)f2bf(a.w) << 16) | f2bf(a.z);
    o.z = ((unsigned)f2bf(b.y) << 16) | f2bf(b.x);
    o.w = ((unsigned)f2bf(b.w) << 16) | f2bf(b.z);
    *(uint4*)(xh + (size_t)i * 4) = o;
}

// ---------------------------------------------------------------------------
// gather: one wave per node, 4 edges per iteration (quarter-wave per edge,
// uint4 = 8 bf16 feats per lane). agg mean (fp32) written into d_out scratch.
// ---------------------------------------------------------------------------
__global__ void gather_kernel(const uint4* __restrict__ xh,   // 16 uint4 per row
                              const int* __restrict__ pos,    // = end after fill
                              const int* __restrict__ deg_cnt,
                              const int* __restrict__ edge_src,
                              float* __restrict__ agg)        // d_out scratch
{
    int tid  = threadIdx.x;
    int node = blockIdx.x * 4 + (tid >> 6);
    int lane = tid & 63;
    int quarter = lane >> 4;     // 0..3  (edge slot within iteration)
    int sub     = lane & 15;     // 0..15 (uint4 within row)
    if (node >= N_NODES) return;

    int end   = pos[node];
    int dcnt  = deg_cnt[node];
    int start = end - dcnt;

    float a0 = 0.f, a1 = 0.f, a2 = 0.f, a3 = 0.f,
          a4 = 0.f, a5 = 0.f, a6 = 0.f, a7 = 0.f;

    for (int b = start; b < end; b += 64) {
        int nb = end - b; if (nb > 64) nb = 64;
        int sid = (b + lane < end) ? edge_src[b + lane] : 0;
        for (int j = 0; j < nb; j += 4) {
            int eidx = j + quarter;
            int s = __shfl(sid, eidx, 64);
            if (eidx < nb) {
                const uint4 v = xh[(size_t)s * 16 + sub];
                a0 += bflo(v.x); a1 += bfhi(v.x);
                a2 += bflo(v.y); a3 += bfhi(v.y);
                a4 += bflo(v.z); a5 += bfhi(v.z);
                a6 += bflo(v.w); a7 += bfhi(v.w);
            }
        }
    }
    // reduce across the 4 quarters (lane ^ 16, lane ^ 32)
    #pragma unroll
    for (int m = 16; m <= 32; m <<= 1) {
        a0 += __shfl_xor(a0, m, 64); a1 += __shfl_xor(a1, m, 64);
        a2 += __shfl_xor(a2, m, 64); a3 += __shfl_xor(a3, m, 64);
        a4 += __shfl_xor(a4, m, 64); a5 += __shfl_xor(a5, m, 64);
        a6 += __shfl_xor(a6, m, 64); a7 += __shfl_xor(a7, m, 64);
    }
    if (quarter == 0) {
        float inv = 1.0f / (float)((dcnt > 1) ? dcnt : 1);
        float4 m0, m1;
        m0.x = a0 * inv; m0.y = a1 * inv; m0.z = a2 * inv; m0.w = a3 * inv;
        m1.x = a4 * inv; m1.y = a5 * inv; m1.z = a6 * inv; m1.w = a7 * inv;
        float* dst = agg + (size_t)node * D_FEAT + sub * 8;
        *(float4*)dst       = m0;
        *(float4*)(dst + 4) = m1;
    }
}

// ---------------------------------------------------------------------------
// weight prep.  Wt2 layout [k][n], k<128 -> W1; k>=128 -> M = agg_W @ W2.
// cvec[n] = b[n] + sum_j agg_b[j]*W2[j][n].
// ---------------------------------------------------------------------------
__global__ void wprep_kernel(const float* __restrict__ agg_W,
                             const float* __restrict__ agg_b,
                             const float* __restrict__ W,
                             const float* __restrict__ b,
                             float* __restrict__ Wt2,
                             float* __restrict__ cvec)
{
    int t = blockIdx.x;    // 0..127
    int n = threadIdx.x;   // 0..127

    Wt2[t * 128 + n] = W[t * 128 + n];            // W1 half, already [k][n]

    float m = 0.0f;
    for (int j = 0; j < 128; ++j)
        m += agg_W[t * 128 + j] * W[(128 + j) * 128 + n];
    Wt2[(128 + t) * 128 + n] = m;

    if (t == 0) {
        float s = b[n];
        for (int j = 0; j < 128; ++j)
            s += agg_b[j] * W[(128 + j) * 128 + n];
        cvec[n] = s;
    }
}

// ---------------------------------------------------------------------------
// fused GEMM (A=[x|agg] @ Wt2^T + c) -> ReLU -> LayerNorm -> out (fp32).
// 256 threads, TM=64 nodes/block; thread (tx=tid&15, ty=tid>>4) owns
// 4 nodes x 8 cols (32 accs).
// Wc is stored DEINTERLEAVED per k-row: cols g*8..g*8+3 at float offset g*4,
// cols g*8+4..g*8+7 at offset 64+g*4.  Reads then use stride tx*4 ->
// start banks {0,4,..,28}, 2 lanes/bank = conflict-free (vs tx*8's 4-way).
// agg aliases out: each block reads only its own nodes' agg before writing.
// ---------------------------------------------------------------------------
__global__ __launch_bounds__(256) void gsage_main(
        const float* __restrict__ x,
        const float* __restrict__ agg,      // aliases `out`
        const float* __restrict__ Wt2,
        const float* __restrict__ cvec,
        const float* __restrict__ gamma,
        const float* __restrict__ beta,
        float* __restrict__ out)
{
    __shared__ float A[TM][APAD];     // 64 x 36 floats = 9.2 KB
    __shared__ float Wc[KB * 128];    // 16 KB, deinterleaved layout

    int tid   = threadIdx.x;
    int tx    = tid & 15;             // 16 col groups x 8 cols
    int ty    = tid >> 4;             // 16 row groups x 4 nodes
    int node0 = blockIdx.x * TM;

    float acc[4][8];
    #pragma unroll
    for (int i = 0; i < 4; ++i)
        #pragma unroll
        for (int j = 0; j < 8; ++j) acc[i][j] = 0.0f;

    for (int c = 0; c < 256 / KB; ++c) {
        int k0 = c * KB;
        // ---- stage A chunk: 64 rows x 32 k (512 float4, 2 per thread) ----
        #pragma unroll
        for (int it = 0; it < 2; ++it) {
            int idx = it * 256 + tid;
            int r  = idx >> 3;
            int kk = (idx & 7) * 4;
            int k  = k0 + kk;
            int node = node0 + r;
            float4 v = make_float4(0.f, 0.f, 0.f, 0.f);
            if (node < N_NODES) {
                const float* src = (k < 128)
                    ? (x   + (size_t)node * D_FEAT + k)
                    : (agg + (size_t)node * D_FEAT + (k - 128));
                v = *(const float4*)src;
            }
            *(float4*)&A[r][kk] = v;
        }
        // ---- stage W chunk, deinterleaving column halves ----
        {
            const float4* src = (const float4*)(Wt2 + k0 * 128);
            float4* dstp = (float4*)Wc;
            #pragma unroll
            for (int i = 0; i < 4; ++i) {
                int idx = i * 256 + tid;     // 0..1023
                int kk  = idx >> 5;          // k-row 0..31
                int f   = idx & 31;          // source float4 within row
                int g   = f >> 1, h = f & 1;
                dstp[kk * 32 + h * 16 + g] = src[idx];
            }
        }
        __syncthreads();

        // ---- inner product ----
        #pragma unroll 8
        for (int kk = 0; kk < KB; ++kk) {
            float a0 = A[ty * 4 + 0][kk];
            float a1 = A[ty * 4 + 1][kk];
            float a2 = A[ty * 4 + 2][kk];
            float a3 = A[ty * 4 + 3][kk];
            float4 w0 = *(const float4*)&Wc[kk * 128 + tx * 4];        // cols tx*8..+3
            float4 w1 = *(const float4*)&Wc[kk * 128 + 64 + tx * 4];   // cols tx*8+4..+7
            acc[0][0] += a0*w0.x; acc[0][1] += a0*w0.y; acc[0][2] += a0*w0.z; acc[0][3] += a0*w0.w;
            acc[0][4] += a0*w1.x; acc[0][5] += a0*w1.y; acc[0][6] += a0*w1.z; acc[0][7] += a0*w1.w;
            acc[1][0] += a1*w0.x; acc[1][1] += a1*w0.y; acc[1][2] += a1*w0.z; acc[1][3] += a1*w0.w;
            acc[1][4] += a1*w1.x; acc[1][5] += a1*w1.y; acc[1][6] += a1*w1.z; acc[1][7] += a1*w1.w;
            acc[2][0] += a2*w0.x; acc[2][1] += a2*w0.y; acc[2][2] += a2*w0.z; acc[2][3] += a2*w0.w;
            acc[2][4] += a2*w1.x; acc[2][5] += a2*w1.y; acc[2][6] += a2*w1.z; acc[2][7] += a2*w1.w;
            acc[3][0] += a3*w0.x; acc[3][1] += a3*w0.y; acc[3][2] += a3*w0.z; acc[3][3] += a3*w0.w;
            acc[3][4] += a3*w1.x; acc[3][5] += a3*w1.y; acc[3][6] += a3*w1.z; acc[3][7] += a3*w1.w;
        }
        __syncthreads();
    }

    // ---- epilogue: +c, ReLU, LayerNorm over 128 cols (16 tx lanes x 8) ----
    float4 cv0 = *(const float4*)(cvec  + tx * 8), cv1 = *(const float4*)(cvec  + tx * 8 + 4);
    float4 gv0 = *(const float4*)(gamma + tx * 8), gv1 = *(const float4*)(gamma + tx * 8 + 4);
    float4 bv0 = *(const float4*)(beta  + tx * 8), bv1 = *(const float4*)(beta  + tx * 8 + 4);
    float cc[8] = {cv0.x,cv0.y,cv0.z,cv0.w,cv1.x,cv1.y,cv1.z,cv1.w};
    float gg[8] = {gv0.x,gv0.y,gv0.z,gv0.w,gv1.x,gv1.y,gv1.z,gv1.w};
    float bb[8] = {bv0.x,bv0.y,bv0.z,bv0.w,bv1.x,bv1.y,bv1.z,bv1.w};

    #pragma unroll
    for (int i = 0; i < 4; ++i) {
        float v[8]; float s1 = 0.f, s2 = 0.f;
        #pragma unroll
        for (int j = 0; j < 8; ++j) {
            float t = acc[i][j] + cc[j];
            t = (t > 0.f) ? t : 0.f;
            v[j] = t; s1 += t; s2 += t * t;
        }
        #pragma unroll
        for (int m = 1; m < 16; m <<= 1) {   // reduce across 16 tx lanes
            s1 += __shfl_xor(s1, m, 64);
            s2 += __shfl_xor(s2, m, 64);
        }
        float mu   = s1 * (1.0f / 128.0f);
        float var  = s2 * (1.0f / 128.0f) - mu * mu;
        float rstd = rsqrtf(var + LN_EPS);
        int node = node0 + ty * 4 + i;
        if (node < N_NODES) {
            float4 o0, o1;
            o0.x = (v[0]-mu)*rstd*gg[0]+bb[0]; o0.y = (v[1]-mu)*rstd*gg[1]+bb[1];
            o0.z = (v[2]-mu)*rstd*gg[2]+bb[2]; o0.w = (v[3]-mu)*rstd*gg[3]+bb[3];
            o1.x = (v[4]-mu)*rstd*gg[4]+bb[4]; o1.y = (v[5]-mu)*rstd*gg[5]+bb[5];
            o1.z = (v[6]-mu)*rstd*gg[6]+bb[6]; o1.w = (v[7]-mu)*rstd*gg[7]+bb[7];
            float* dst = out + (size_t)node * D_FEAT + tx * 8;
            *(float4*)dst       = o0;
            *(float4*)(dst + 4) = o1;
        }
    }
}

// ---------------------------------------------------------------------------
extern "C" void kernel_launch(void* const* d_in, const int* in_sizes, int n_in,
                              void* d_out, int out_size, void* d_ws, size_t ws_size,
                              hipStream_t stream) {
    const float* x     = (const float*)d_in[0];
    const int*   ei    = (const int*)d_in[1];
    const float* agg_W = (const float*)d_in[2];
    const float* agg_b = (const float*)d_in[3];
    const float* W     = (const float*)d_in[4];
    const float* b     = (const float*)d_in[5];
    const float* gamma = (const float*)d_in[6];
    const float* beta  = (const float*)d_in[7];
    float*       out   = (float*)d_out;

    size_t out_bytes = (size_t)out_size * sizeof(float);

    if (n_in != 8)                       { hipMemsetAsync(d_out, 0x45, out_bytes, stream); return; }
    if (in_sizes[0] != N_NODES * D_FEAT) { hipMemsetAsync(d_out, 0x48, out_bytes, stream); return; }
    if (in_sizes[1] != 2 * N_EDGES)      { hipMemsetAsync(d_out, 0x49, out_bytes, stream); return; }
    if (out_size != N_NODES * D_FEAT)    { hipMemsetAsync(d_out, 0x47, out_bytes, stream); return; }

    // workspace layout (4-byte elements)
    int*   deg_cnt  = (int*)d_ws;                  // 50000
    int*   pos      = deg_cnt + N_NODES;           // 50000
    int*   edge_src = pos + N_NODES;               // 800000
    float* Wt2      = (float*)(edge_src + N_EDGES);// 256*128
    float* cvec     = Wt2 + 256 * 128;             // 128
    int*   bsum     = (int*)(cvec + 128);          // NBLK
    int*   boff     = bsum + NBLK;                 // NBLK
    unsigned int* xh = (unsigned int*)(boff + NBLK); // 50000*64 uints (bf16 x)
    size_t need_ws = ((size_t)N_NODES * 2 + N_EDGES + 256 * 128 + 128 + 2 * NBLK
                      + (size_t)N_NODES * 64) * 4;
    if (ws_size < need_ws)               { hipMemsetAsync(d_out, 0x46, out_bytes, stream); return; }

    hipMemsetAsync(deg_cnt, 0, N_NODES * sizeof(int), stream);
    hist_kernel<<<(N_EDGES + 255) / 256, 256, 0, stream>>>(ei, deg_cnt);
    blocksum_kernel<<<NBLK, 256, 0, stream>>>(deg_cnt, bsum);
    scanblk_kernel<<<1, 256, 0, stream>>>(bsum, boff);
    scanpos_kernel<<<NBLK, 256, 0, stream>>>(deg_cnt, boff, pos);
    fill_kernel<<<(N_EDGES + 255) / 256, 256, 0, stream>>>(ei, pos, edge_src);
    wprep_kernel<<<128, 128, 0, stream>>>(agg_W, agg_b, W, b, Wt2, cvec);
    cvt_kernel<<<(N_NODES * D_FEAT / 8 + 255) / 256, 256, 0, stream>>>(x, xh);
    gather_kernel<<<(N_NODES + 3) / 4, 256, 0, stream>>>(
        (const uint4*)xh, pos, deg_cnt, edge_src, out);
    gsage_main<<<(N_NODES + TM - 1) / TM, 256, 0, stream>>>(
        x, out, Wt2, cvec, gamma, beta, out);
}